// Round 4
// baseline (120.206 us; speedup 1.0000x reference)
//
#include <hip/hip_runtime.h>
#include <math.h>

// Problem constants
#define NB 8
#define NN 128
static constexpr float NEGV = -1000000.0f;

// One workgroup per (b, r). 256 threads = 4 waves. Flash-style online softmax
// over 4 s-tiles of 32, double-buffered register tile, 4 blocks/CU resident.
// lane l: e = l>>5, c4 = l&31. Wave w owns s_loc = 8w..8w+7 of each tile.
__global__ __launch_bounds__(256, 4)
void edge_attn_kernel(const float* __restrict__ edge_msgs,
                      const float* __restrict__ node_states,
                      const float* __restrict__ W,
                      const float* __restrict__ bvec,
                      const int*   __restrict__ edges,
                      float* __restrict__ out) {
    const int blk = blockIdx.x;
    const int b = blk >> 7;
    const int r = blk & 127;

    const int t  = threadIdx.x;
    const int w  = t >> 6;       // wave 0..3
    const int l  = t & 63;
    const int e  = l >> 5;       // 0/1
    const int c4 = l & 31;

    // softmax-group identity (fixed across tiles): group g = sh*2 + se, lane j = s_loc
    const int g  = t >> 5;       // 0..7
    const int j  = t & 31;       // s within tile
    const int se = g & 1;
    const int sh = g >> 1;

    __shared__ float sval[32 * 9];       // tile scores [s_loc*9 + e*4 + h]
    __shared__ float wtile[32 * 9];      // tile exp-weights, same layout
    __shared__ float ebias[128 * 2];     // [s*2 + e]
    __shared__ float nodep[4];
    __shared__ float corrbuf[8];         // [h*2 + e]
    __shared__ float lbuf[8];            // [h*2 + e]
    __shared__ float outbuf[4][4][128];  // [wave][h][c]

    // ---- W_msg fragment for this lane's c-chunk
    float4 wm0 = *(const float4*)(W +   0 + c4 * 4);
    float4 wm1 = *(const float4*)(W + 256 + c4 * 4);
    float4 wm2 = *(const float4*)(W + 512 + c4 * 4);
    float4 wm3 = *(const float4*)(W + 768 + c4 * 4);

    // ---- stream base for this (b, r): per-s stride = 128*2*128 floats
    const float* bp = edge_msgs
        + (size_t)b * (NN * NN * 256)
        + (size_t)r * 256
        + e * 128 + c4 * 4;

    float4 v[2][8];
    // prologue: issue tile-0 loads immediately
    #pragma unroll
    for (int si = 0; si < 8; ++si)
        v[0][si] = *(const float4*)(bp + (size_t)(8 * w + si) * 32768);

    // ---- node projection: wave 0, 64-lane reduce
    if (w == 0) {
        float2 nv  = *(const float2*)(node_states + ((size_t)b * NN + r) * 128 + l * 2);
        float2 wn0 = *(const float2*)(W + 128 + l * 2);
        float2 wn1 = *(const float2*)(W + 384 + l * 2);
        float2 wn2 = *(const float2*)(W + 640 + l * 2);
        float2 wn3 = *(const float2*)(W + 896 + l * 2);
        float np0 = nv.x * wn0.x + nv.y * wn0.y;
        float np1 = nv.x * wn1.x + nv.y * wn1.y;
        float np2 = nv.x * wn2.x + nv.y * wn2.y;
        float np3 = nv.x * wn3.x + nv.y * wn3.y;
        #pragma unroll
        for (int m = 32; m >= 1; m >>= 1) {
            np0 += __shfl_xor(np0, m);
            np1 += __shfl_xor(np1, m);
            np2 += __shfl_xor(np2, m);
            np3 += __shfl_xor(np3, m);
        }
        if (l == 0) { nodep[0] = np0; nodep[1] = np1; nodep[2] = np2; nodep[3] = np3; }
    }

    // ---- edge mask bias: 256 threads, one int each
    {
        int s  = t >> 1;
        int ec = t & 1;
        int ev = edges[(((size_t)b * NN + s) * NN + r) * 3 + 1 + ec];
        ebias[s * 2 + ec] = (1.0f - (float)ev) * NEGV;
    }
    __syncthreads();

    const float bb = bvec[sh] + nodep[sh];

    float m_run = -INFINITY, l_run = 0.0f;
    float4 a0 = {0,0,0,0}, a1 = {0,0,0,0}, a2 = {0,0,0,0}, a3 = {0,0,0,0};

    const int  hsel = l & 3;
    const bool o1   = (l & 1) != 0;
    const bool o2   = (l & 2) != 0;

    #pragma unroll
    for (int T = 0; T < 4; ++T) {
        const int cur = T & 1;
        const int nxt = cur ^ 1;
        // issue next-tile loads (overlap with this tile's compute)
        if (T < 3) {
            #pragma unroll
            for (int si = 0; si < 8; ++si)
                v[nxt][si] = *(const float4*)(bp + (size_t)(32 * (T + 1) + 8 * w + si) * 32768);
        }
        // ---- scores for this tile: quad swap-select reduce + xor4/8/16 butterfly
        #pragma unroll
        for (int si = 0; si < 8; ++si) {
            float4 d = v[cur][si];
            float p0 = d.x * wm0.x + d.y * wm0.y + d.z * wm0.z + d.w * wm0.w;
            float p1 = d.x * wm1.x + d.y * wm1.y + d.z * wm1.z + d.w * wm1.w;
            float p2 = d.x * wm2.x + d.y * wm2.y + d.z * wm2.z + d.w * wm2.w;
            float p3 = d.x * wm3.x + d.y * wm3.y + d.z * wm3.z + d.w * wm3.w;
            float x01 = o1 ? p1 : p0, y01 = o1 ? p0 : p1;
            float x23 = o1 ? p3 : p2, y23 = o1 ? p2 : p3;
            float r01 = x01 + __shfl_xor(y01, 1);
            float r23 = x23 + __shfl_xor(y23, 1);
            float x2 = o2 ? r23 : r01, y2 = o2 ? r01 : r23;
            float val = x2 + __shfl_xor(y2, 2);   // lane (l&3)=h holds quad sum
            val += __shfl_xor(val, 4);
            val += __shfl_xor(val, 8);
            val += __shfl_xor(val, 16);           // full 32-lane-half sum
            if ((l & 31) < 4)
                sval[(8 * w + si) * 9 + e * 4 + hsel] = val;
        }
        __syncthreads();

        // ---- online softmax update: group g=(sh,se), lane j = s_loc
        {
            float x = sval[j * 9 + se * 4 + sh] + bb;
            x = x > 0.f ? x : expm1f(x);
            float y = x + ebias[(32 * T + j) * 2 + se];
            float mt = y;
            #pragma unroll
            for (int m = 16; m >= 1; m >>= 1) mt = fmaxf(mt, __shfl_xor(mt, m));
            float m_new = fmaxf(m_run, mt);
            float corr  = __expf(m_run - m_new);
            float p     = __expf(y - m_new);
            float ls = p;
            #pragma unroll
            for (int m = 16; m >= 1; m >>= 1) ls += __shfl_xor(ls, m);
            l_run = l_run * corr + ls;
            m_run = m_new;
            wtile[j * 9 + se * 4 + sh] = p;
            if (j == 0) corrbuf[sh * 2 + se] = corr;
        }
        __syncthreads();

        // ---- aggregate this tile with rescale
        {
            float c0 = corrbuf[0 * 2 + e];
            float c1 = corrbuf[1 * 2 + e];
            float c2 = corrbuf[2 * 2 + e];
            float c3 = corrbuf[3 * 2 + e];
            a0.x *= c0; a0.y *= c0; a0.z *= c0; a0.w *= c0;
            a1.x *= c1; a1.y *= c1; a1.z *= c1; a1.w *= c1;
            a2.x *= c2; a2.y *= c2; a2.z *= c2; a2.w *= c2;
            a3.x *= c3; a3.y *= c3; a3.z *= c3; a3.w *= c3;
            #pragma unroll
            for (int si = 0; si < 8; ++si) {
                int sl = 8 * w + si;
                float4 d = v[cur][si];
                float w0 = wtile[sl * 9 + e * 4 + 0];
                float w1 = wtile[sl * 9 + e * 4 + 1];
                float w2 = wtile[sl * 9 + e * 4 + 2];
                float w3 = wtile[sl * 9 + e * 4 + 3];
                a0.x += w0 * d.x; a0.y += w0 * d.y; a0.z += w0 * d.z; a0.w += w0 * d.w;
                a1.x += w1 * d.x; a1.y += w1 * d.y; a1.z += w1 * d.z; a1.w += w1 * d.w;
                a2.x += w2 * d.x; a2.y += w2 * d.y; a2.z += w2 * d.z; a2.w += w2 * d.w;
                a3.x += w3 * d.x; a3.y += w3 * d.y; a3.z += w3 * d.z; a3.w += w3 * d.w;
            }
        }
        __syncthreads();   // protect sval/wtile before next tile overwrites
    }

    // ---- final: store l_run, divide, fold e, cross-wave reduce, store
    if (j == 0) lbuf[sh * 2 + se] = l_run;
    __syncthreads();
    {
        float i0 = 1.0f / lbuf[0 * 2 + e];
        float i1 = 1.0f / lbuf[1 * 2 + e];
        float i2 = 1.0f / lbuf[2 * 2 + e];
        float i3 = 1.0f / lbuf[3 * 2 + e];
        a0.x *= i0; a0.y *= i0; a0.z *= i0; a0.w *= i0;
        a1.x *= i1; a1.y *= i1; a1.z *= i1; a1.w *= i1;
        a2.x *= i2; a2.y *= i2; a2.z *= i2; a2.w *= i2;
        a3.x *= i3; a3.y *= i3; a3.z *= i3; a3.w *= i3;
    }
    a0.x += __shfl_xor(a0.x, 32); a0.y += __shfl_xor(a0.y, 32); a0.z += __shfl_xor(a0.z, 32); a0.w += __shfl_xor(a0.w, 32);
    a1.x += __shfl_xor(a1.x, 32); a1.y += __shfl_xor(a1.y, 32); a1.z += __shfl_xor(a1.z, 32); a1.w += __shfl_xor(a1.w, 32);
    a2.x += __shfl_xor(a2.x, 32); a2.y += __shfl_xor(a2.y, 32); a2.z += __shfl_xor(a2.z, 32); a2.w += __shfl_xor(a2.w, 32);
    a3.x += __shfl_xor(a3.x, 32); a3.y += __shfl_xor(a3.y, 32); a3.z += __shfl_xor(a3.z, 32); a3.w += __shfl_xor(a3.w, 32);

    if (e == 0) {
        *(float4*)&outbuf[w][0][c4 * 4] = a0;
        *(float4*)&outbuf[w][1][c4 * 4] = a1;
        *(float4*)&outbuf[w][2][c4 * 4] = a2;
        *(float4*)&outbuf[w][3][c4 * 4] = a3;
    }
    __syncthreads();

    #pragma unroll
    for (int k = 0; k < 2; ++k) {
        int idx = t + 256 * k;          // h*128 + c
        int h = idx >> 7;
        int c = idx & 127;
        float sv = outbuf[0][h][c] + outbuf[1][h][c] + outbuf[2][h][c] + outbuf[3][h][c];
        out[((size_t)b * NN + r) * 512 + idx] = sv;
    }
}

extern "C" void kernel_launch(void* const* d_in, const int* in_sizes, int n_in,
                              void* d_out, int out_size, void* d_ws, size_t ws_size,
                              hipStream_t stream) {
    const float* edge_msgs   = (const float*)d_in[0];
    const float* node_states = (const float*)d_in[1];
    const float* W           = (const float*)d_in[2];
    const float* bvec        = (const float*)d_in[3];
    const int*   edges       = (const int*)d_in[4];
    float* out = (float*)d_out;

    edge_attn_kernel<<<dim3(NB * NN), dim3(256), 0, stream>>>(
        edge_msgs, node_states, W, bvec, edges, out);
}

// Round 5
// 115.896 us; speedup vs baseline: 1.0372x; 1.0372x over previous
//
#include <hip/hip_runtime.h>
#include <math.h>

// Problem constants
#define NB 8
#define NN 128
static constexpr float NEGV = -1000000.0f;

// One workgroup per (b, r). 256 threads = 4 waves. Flash-style online softmax
// over 4 s-tiles of 32. Double-buffered NAMED register tiles va/vb (literal
// indices only -> no scratch, rule #20). 4 blocks/CU resident.
// lane l: e = l>>5, c4 = l&31. Wave w owns s_loc = 8w..8w+7 of each tile.
__global__ __launch_bounds__(256, 4)
void edge_attn_kernel(const float* __restrict__ edge_msgs,
                      const float* __restrict__ node_states,
                      const float* __restrict__ W,
                      const float* __restrict__ bvec,
                      const int*   __restrict__ edges,
                      float* __restrict__ out) {
    const int blk = blockIdx.x;
    const int b = blk >> 7;
    const int r = blk & 127;

    const int t  = threadIdx.x;
    const int w  = t >> 6;       // wave 0..3
    const int l  = t & 63;
    const int e  = l >> 5;       // 0/1
    const int c4 = l & 31;

    // softmax-group identity: group g = sh*2 + se, lane j = s within tile
    const int g  = t >> 5;       // 0..7
    const int j  = t & 31;
    const int se = g & 1;
    const int sh = g >> 1;

    __shared__ float sval[2][32 * 9];    // [parity][s_loc*9 + e*4 + h]
    __shared__ float wtile[2][32 * 9];
    __shared__ float ebias[128 * 2];     // [s*2 + e]
    __shared__ float nodep[4];
    __shared__ float corrbuf[2][8];      // [parity][h*2 + e]
    __shared__ float lbuf[8];            // [h*2 + e]
    __shared__ float outbuf[4][4][128];  // [wave][h][c]

    // ---- W_msg fragment for this lane's c-chunk
    float4 wm0 = *(const float4*)(W +   0 + c4 * 4);
    float4 wm1 = *(const float4*)(W + 256 + c4 * 4);
    float4 wm2 = *(const float4*)(W + 512 + c4 * 4);
    float4 wm3 = *(const float4*)(W + 768 + c4 * 4);

    // ---- stream base for this (b, r): per-s stride = 128*2*128 floats
    const float* bp = edge_msgs
        + (size_t)b * (NN * NN * 256)
        + (size_t)r * 256
        + e * 128 + c4 * 4;

    float4 va[8], vb[8];
    // prologue: issue tile-0 loads immediately
    #pragma unroll
    for (int si = 0; si < 8; ++si)
        va[si] = *(const float4*)(bp + (size_t)(8 * w + si) * 32768);

    // ---- node projection: wave 0, 64-lane reduce
    if (w == 0) {
        float2 nv  = *(const float2*)(node_states + ((size_t)b * NN + r) * 128 + l * 2);
        float2 wn0 = *(const float2*)(W + 128 + l * 2);
        float2 wn1 = *(const float2*)(W + 384 + l * 2);
        float2 wn2 = *(const float2*)(W + 640 + l * 2);
        float2 wn3 = *(const float2*)(W + 896 + l * 2);
        float np0 = nv.x * wn0.x + nv.y * wn0.y;
        float np1 = nv.x * wn1.x + nv.y * wn1.y;
        float np2 = nv.x * wn2.x + nv.y * wn2.y;
        float np3 = nv.x * wn3.x + nv.y * wn3.y;
        #pragma unroll
        for (int m = 32; m >= 1; m >>= 1) {
            np0 += __shfl_xor(np0, m);
            np1 += __shfl_xor(np1, m);
            np2 += __shfl_xor(np2, m);
            np3 += __shfl_xor(np3, m);
        }
        if (l == 0) { nodep[0] = np0; nodep[1] = np1; nodep[2] = np2; nodep[3] = np3; }
    }

    // ---- edge mask bias: 256 threads, one int each
    {
        int s  = t >> 1;
        int ec = t & 1;
        int ev = edges[(((size_t)b * NN + s) * NN + r) * 3 + 1 + ec];
        ebias[s * 2 + ec] = (1.0f - (float)ev) * NEGV;
    }
    __syncthreads();

    const float bb = bvec[sh] + nodep[sh];

    float m_run = -INFINITY, l_run = 0.0f;
    float4 a0 = {0,0,0,0}, a1 = {0,0,0,0}, a2 = {0,0,0,0}, a3 = {0,0,0,0};

    const int  hsel = l & 3;
    const bool o1   = (l & 1) != 0;
    const bool o2   = (l & 2) != 0;

// One flash tile: P = LDS parity (literal), Tl = tile index (literal),
// CUR/NXT = named register buffers, DOLOAD = prefetch next tile.
#define TILE(P, Tl, CUR, NXT, DOLOAD)                                          \
  {                                                                            \
    if (DOLOAD) {                                                              \
      _Pragma("unroll")                                                        \
      for (int si = 0; si < 8; ++si)                                           \
        NXT[si] = *(const float4*)(bp + (size_t)(32 * ((Tl) + 1) + 8 * w + si) * 32768); \
    }                                                                          \
    _Pragma("unroll")                                                          \
    for (int si = 0; si < 8; ++si) {                                           \
      float4 d = CUR[si];                                                      \
      float p0 = d.x * wm0.x + d.y * wm0.y + d.z * wm0.z + d.w * wm0.w;        \
      float p1 = d.x * wm1.x + d.y * wm1.y + d.z * wm1.z + d.w * wm1.w;        \
      float p2 = d.x * wm2.x + d.y * wm2.y + d.z * wm2.z + d.w * wm2.w;        \
      float p3 = d.x * wm3.x + d.y * wm3.y + d.z * wm3.z + d.w * wm3.w;        \
      float x01 = o1 ? p1 : p0, y01 = o1 ? p0 : p1;                            \
      float x23 = o1 ? p3 : p2, y23 = o1 ? p2 : p3;                            \
      float r01 = x01 + __shfl_xor(y01, 1);                                    \
      float r23 = x23 + __shfl_xor(y23, 1);                                    \
      float x2 = o2 ? r23 : r01, y2 = o2 ? r01 : r23;                          \
      float val = x2 + __shfl_xor(y2, 2);                                      \
      val += __shfl_xor(val, 4);                                               \
      val += __shfl_xor(val, 8);                                               \
      val += __shfl_xor(val, 16);                                              \
      if ((l & 31) < 4) sval[P][(8 * w + si) * 9 + e * 4 + hsel] = val;        \
    }                                                                          \
    __syncthreads();                                                           \
    {                                                                          \
      float x = sval[P][j * 9 + se * 4 + sh] + bb;                             \
      x = x > 0.f ? x : expm1f(x);                                             \
      float y = x + ebias[(32 * (Tl) + j) * 2 + se];                           \
      float mt = y;                                                            \
      _Pragma("unroll")                                                        \
      for (int m = 16; m >= 1; m >>= 1) mt = fmaxf(mt, __shfl_xor(mt, m));     \
      float m_new = fmaxf(m_run, mt);                                          \
      float corr = __expf(m_run - m_new);                                      \
      float p = __expf(y - m_new);                                             \
      float ls = p;                                                            \
      _Pragma("unroll")                                                        \
      for (int m = 16; m >= 1; m >>= 1) ls += __shfl_xor(ls, m);               \
      l_run = l_run * corr + ls;                                               \
      m_run = m_new;                                                           \
      wtile[P][j * 9 + se * 4 + sh] = p;                                       \
      if (j == 0) corrbuf[P][sh * 2 + se] = corr;                              \
    }                                                                          \
    __syncthreads();                                                           \
    {                                                                          \
      float c0 = corrbuf[P][0 * 2 + e];                                        \
      float c1 = corrbuf[P][1 * 2 + e];                                        \
      float c2 = corrbuf[P][2 * 2 + e];                                        \
      float c3 = corrbuf[P][3 * 2 + e];                                        \
      a0.x *= c0; a0.y *= c0; a0.z *= c0; a0.w *= c0;                          \
      a1.x *= c1; a1.y *= c1; a1.z *= c1; a1.w *= c1;                          \
      a2.x *= c2; a2.y *= c2; a2.z *= c2; a2.w *= c2;                          \
      a3.x *= c3; a3.y *= c3; a3.z *= c3; a3.w *= c3;                          \
      _Pragma("unroll")                                                        \
      for (int si = 0; si < 8; ++si) {                                         \
        int sl = 8 * w + si;                                                   \
        float4 d = CUR[si];                                                    \
        float w0 = wtile[P][sl * 9 + e * 4 + 0];                               \
        float w1 = wtile[P][sl * 9 + e * 4 + 1];                               \
        float w2 = wtile[P][sl * 9 + e * 4 + 2];                               \
        float w3 = wtile[P][sl * 9 + e * 4 + 3];                               \
        a0.x += w0 * d.x; a0.y += w0 * d.y; a0.z += w0 * d.z; a0.w += w0 * d.w; \
        a1.x += w1 * d.x; a1.y += w1 * d.y; a1.z += w1 * d.z; a1.w += w1 * d.w; \
        a2.x += w2 * d.x; a2.y += w2 * d.y; a2.z += w2 * d.z; a2.w += w2 * d.w; \
        a3.x += w3 * d.x; a3.y += w3 * d.y; a3.z += w3 * d.z; a3.w += w3 * d.w; \
      }                                                                        \
    }                                                                          \
  }

    TILE(0, 0, va, vb, true)
    TILE(1, 1, vb, va, true)
    TILE(0, 2, va, vb, true)
    TILE(1, 3, vb, va, false)
#undef TILE

    // ---- final: store l_run, divide, fold e, cross-wave reduce, store
    if (j == 0) lbuf[sh * 2 + se] = l_run;
    __syncthreads();
    {
        float i0 = 1.0f / lbuf[0 * 2 + e];
        float i1 = 1.0f / lbuf[1 * 2 + e];
        float i2 = 1.0f / lbuf[2 * 2 + e];
        float i3 = 1.0f / lbuf[3 * 2 + e];
        a0.x *= i0; a0.y *= i0; a0.z *= i0; a0.w *= i0;
        a1.x *= i1; a1.y *= i1; a1.z *= i1; a1.w *= i1;
        a2.x *= i2; a2.y *= i2; a2.z *= i2; a2.w *= i2;
        a3.x *= i3; a3.y *= i3; a3.z *= i3; a3.w *= i3;
    }
    a0.x += __shfl_xor(a0.x, 32); a0.y += __shfl_xor(a0.y, 32); a0.z += __shfl_xor(a0.z, 32); a0.w += __shfl_xor(a0.w, 32);
    a1.x += __shfl_xor(a1.x, 32); a1.y += __shfl_xor(a1.y, 32); a1.z += __shfl_xor(a1.z, 32); a1.w += __shfl_xor(a1.w, 32);
    a2.x += __shfl_xor(a2.x, 32); a2.y += __shfl_xor(a2.y, 32); a2.z += __shfl_xor(a2.z, 32); a2.w += __shfl_xor(a2.w, 32);
    a3.x += __shfl_xor(a3.x, 32); a3.y += __shfl_xor(a3.y, 32); a3.z += __shfl_xor(a3.z, 32); a3.w += __shfl_xor(a3.w, 32);

    if (e == 0) {
        *(float4*)&outbuf[w][0][c4 * 4] = a0;
        *(float4*)&outbuf[w][1][c4 * 4] = a1;
        *(float4*)&outbuf[w][2][c4 * 4] = a2;
        *(float4*)&outbuf[w][3][c4 * 4] = a3;
    }
    __syncthreads();

    #pragma unroll
    for (int k = 0; k < 2; ++k) {
        int idx = t + 256 * k;          // h*128 + c
        int h = idx >> 7;
        int c = idx & 127;
        float sv = outbuf[0][h][c] + outbuf[1][h][c] + outbuf[2][h][c] + outbuf[3][h][c];
        out[((size_t)b * NN + r) * 512 + idx] = sv;
    }
}

extern "C" void kernel_launch(void* const* d_in, const int* in_sizes, int n_in,
                              void* d_out, int out_size, void* d_ws, size_t ws_size,
                              hipStream_t stream) {
    const float* edge_msgs   = (const float*)d_in[0];
    const float* node_states = (const float*)d_in[1];
    const float* W           = (const float*)d_in[2];
    const float* bvec        = (const float*)d_in[3];
    const int*   edges       = (const int*)d_in[4];
    float* out = (float*)d_out;

    edge_attn_kernel<<<dim3(NB * NN), dim3(256), 0, stream>>>(
        edge_msgs, node_states, W, bvec, edges, out);
}